// Round 13
// baseline (1343.806 us; speedup 1.0000x reference)
//
#include <hip/hip_runtime.h>
#include <stdint.h>

#define HH 4096
#define WW 4096
#define CC 3
#define NLOOP 1000
#define NCOPY 8192
#define NTHR 256
#define N4 ((CC * HH * WW) / 4)
#define CSTRIDE (NCOPY * NTHR)
static_assert(N4 == 6 * CSTRIDE, "copy loop must be exactly 6 iterations");

typedef float vfloat4 __attribute__((ext_vector_type(4)));

// JAX threefry2x32 (20 rounds), exact port of _threefry2x32_lowering.
__device__ __forceinline__ void tf2x32(uint32_t k0, uint32_t k1,
                                       uint32_t x0, uint32_t x1,
                                       uint32_t& o0, uint32_t& o1) {
  const uint32_t ks2 = k0 ^ k1 ^ 0x1BD11BDAu;
  x0 += k0; x1 += k1;
#define ROTL_(v,r) (((v)<<(r))|((v)>>(32-(r))))
#define RND_(r) { x0 += x1; x1 = ROTL_(x1,(r)); x1 ^= x0; }
  RND_(13) RND_(15) RND_(26) RND_(6)
  x0 += k1; x1 += ks2 + 1u;
  RND_(17) RND_(29) RND_(16) RND_(24)
  x0 += ks2; x1 += k0 + 2u;
  RND_(13) RND_(15) RND_(26) RND_(6)
  x0 += k0; x1 += k1 + 3u;
  RND_(17) RND_(29) RND_(16) RND_(24)
  x0 += k1; x1 += ks2 + 4u;
  RND_(13) RND_(15) RND_(26) RND_(6)
  x0 += ks2; x1 += k0 + 5u;
  o0 = x0; o1 = x1;
#undef RND_
#undef ROTL_
}

// 32-bit random_bits under partitionable threefry: XOR of the two output words.
__device__ __forceinline__ uint32_t rb32(uint32_t k0, uint32_t k1,
                                         uint32_t x0, uint32_t x1) {
  uint32_t o0, o1;
  tf2x32(k0, k1, x0, x1, o0, o1);
  return o0 ^ o1;
}

// Single dispatch.
//  blocks [0,NLOOP): desc (geometry+perm in LDS) -> publish geo -> spin cnt0
//    -> live mask from geo -> spin cnt1 (copy done) -> scatter.
//  blocks [NLOOP, NLOOP+NCOPY): stream copy img->out (plain loads: L3 keeps
//    input warm; NT stores: write-once output bypasses caches), then bump cnt1.
// Deadlock-free: 1000 waiting blocks << ~2048 co-resident blocks, so copy
// blocks always have CU slots regardless of dispatch order.
__global__ __launch_bounds__(NTHR) void k_all(
    const int* __restrict__ seedp, int4* __restrict__ geo,
    unsigned int* __restrict__ cnt,
    const float* __restrict__ in, float* __restrict__ out) {
  const int b = blockIdx.x;
  const int tid = threadIdx.x;

  if (b >= NLOOP) {
    // ---- copy path: exactly 6 strided float4s per thread ----
    const vfloat4* __restrict__ in4 = (const vfloat4*)in;
    vfloat4* __restrict__ out4 = (vfloat4*)out;
    const int idx = (b - NLOOP) * NTHR + tid;
    #pragma unroll
    for (int k = 0; k < 6; ++k) {
      const int i = idx + k * CSTRIDE;
      vfloat4 v = in4[i];
      __builtin_nontemporal_store(v, &out4[i]);
    }
    __syncthreads();               // compiler drains vmcnt before barrier
    if (tid == 0) {
      __threadfence();             // device-scope release of this block's stores
      atomicAdd(&cnt[1], 1u);
    }
    return;
  }

  // ---- desc path (window i = b) ----
  const int i = b;
  const uint32_t K1 = (uint32_t)seedp[0];

  __shared__ uint32_t rb[CC * 64];
  __shared__ unsigned char mlist[64];
  __shared__ unsigned char srcbuf[CC][64];

  uint32_t k0, k1, a0, a1;
  tf2x32(0u, K1, 0u, (uint32_t)i, k0, k1);

  uint32_t kh0,kh1,kw0,kw1,kp0,kp1,kq0,kq1,kr0,kr1;
  tf2x32(k0,k1,0u,0u,kh0,kh1);   // kh
  tf2x32(k0,k1,0u,1u,kw0,kw1);   // kw
  tf2x32(k0,k1,0u,2u,kp0,kp1);   // kph
  tf2x32(k0,k1,0u,3u,kq0,kq1);   // kpw
  tf2x32(k0,k1,0u,4u,kr0,kr1);   // kperm

  // 192 uniform draws for kperm, one per thread 0..191
  if (tid < CC * 64) rb[tid] = rb32(kr0, kr1, 0u, (uint32_t)tid) >> 9;

  tf2x32(kh0,kh1,0u,1u,a0,a1);   // randint internal split -> k2
  const int wsh = 1 + (int)(rb32(a0,a1,0u,0u) & 7u);
  tf2x32(kw0,kw1,0u,1u,a0,a1);
  const int wsw = 1 + (int)(rb32(a0,a1,0u,0u) & 7u);

  const float uh = __uint_as_float(0x3F800000u | (rb32(kp0,kp1,0u,0u) >> 9)) - 1.0f;
  const float uw = __uint_as_float(0x3F800000u | (rb32(kq0,kq1,0u,0u) >> 9)) - 1.0f;

  const int ph = (int)(uh * (float)(HH - wsh + 1));
  const int pw = (int)(uw * (float)(WW - wsw + 1));
  const int psh = min(ph, HH - 8);
  const int psw = min(pw, WW - 8);
  const int offh = ph - psh;
  const int offw = pw - psw;

  const uint32_t colm = ((1u << wsw) - 1u) << offw;
  unsigned long long rows = (wsh == 8) ? ~0ull : ((1ull << (8 * wsh)) - 1ull);
  rows <<= (8 * offh);
  const unsigned long long mask =
      rows & (0x0101010101010101ull * (unsigned long long)colm);

  if (tid < 64) {
    srcbuf[0][tid] = (unsigned char)tid;
    srcbuf[1][tid] = (unsigned char)tid;
    srcbuf[2][tid] = (unsigned char)tid;
    const int ordinal =
        __popcll(mask & ((tid == 0) ? 0ull : ((1ull << tid) - 1ull)));
    if ((mask >> tid) & 1ull) mlist[ordinal] = (unsigned char)tid;
  }
  if (tid == 0) {
    geo[i] = make_int4(ph, pw, wsh, wsw);
    __threadfence();               // release geo
    atomicAdd(&cnt[0], 1u);
  }
  __syncthreads();   // rb, mlist, identity srcbuf ready

  // stable argsort rank -> permutation (dest mlist[rank] <- src q)
  if (tid < CC * 64) {
    const int c = tid >> 6, q = tid & 63;
    if ((mask >> q) & 1ull) {
      const uint32_t myk = rb[(c << 6) | q];
      int rank = 0;
      for (int q2 = 0; q2 < 64; ++q2) {
        if ((mask >> q2) & 1ull) {
          const uint32_t k2 = rb[(c << 6) | q2];
          if (k2 < myk || (k2 == myk && q2 < q)) ++rank;
        }
      }
      srcbuf[c][mlist[rank]] = (unsigned char)q;
    }
  }

  // ---- wait for all geometries, then live mask ----
  if (tid == 0) {
    while (__hip_atomic_load(&cnt[0], __ATOMIC_ACQUIRE,
                             __HIP_MEMORY_SCOPE_AGENT) < (unsigned)NLOOP)
      __builtin_amdgcn_s_sleep(1);
  }
  __syncthreads();
  __threadfence();   // acquire for geo reads on every thread

  unsigned long long clr = 0ull;
  for (int j = i + 1 + tid; j < NLOOP; j += NTHR) {
    const int4 g = geo[j];          // {ph, pw, wsh, wsw}
    const int r0 = max(0, g.x - psh), r1 = min(8, g.x + g.z - psh);
    const int c0 = max(0, g.y - psw), c1 = min(8, g.y + g.w - psw);
    if (r0 < r1 && c0 < c1) {
      const uint32_t cm = ((1u << (c1 - c0)) - 1u) << c0;
      const int nr = r1 - r0;
      unsigned long long rr = (nr == 8) ? ~0ull : ((1ull << (8 * nr)) - 1ull);
      rr <<= (8 * r0);
      clr |= rr & (0x0101010101010101ull * (unsigned long long)cm);
    }
  }
  #pragma unroll
  for (int m = 32; m > 0; m >>= 1) clr |= __shfl_xor(clr, m, 64);
  __shared__ unsigned long long sh[4];
  if ((tid & 63) == 0) sh[tid >> 6] = clr;
  __syncthreads();
  const unsigned long long live = mask & ~(sh[0] | sh[1] | sh[2] | sh[3]);

  // ---- wait for copy completion, then scatter ----
  if (tid == 0) {
    while (__hip_atomic_load(&cnt[1], __ATOMIC_ACQUIRE,
                             __HIP_MEMORY_SCOPE_AGENT) < (unsigned)NCOPY)
      __builtin_amdgcn_s_sleep(1);
  }
  __syncthreads();
  __threadfence();

  if (tid < CC * 64) {
    const int c = tid >> 6, q = tid & 63;
    if ((live >> q) & 1ull) {
      const int s = srcbuf[c][q];
      const size_t base = (size_t)c * (size_t)HH * (size_t)WW;
      out[base + (size_t)(psh + (q >> 3)) * WW + (size_t)(psw + (q & 7))] =
          in[base + (size_t)(psh + (s >> 3)) * WW + (size_t)(psw + (s & 7))];
    }
  }
}

extern "C" void kernel_launch(void* const* d_in, const int* in_sizes, int n_in,
                              void* d_out, int out_size, void* d_ws, size_t ws_size,
                              hipStream_t stream) {
  const float* img = (const float*)d_in[0];
  const int* seed = (const int*)d_in[1];
  float* out = (float*)d_out;
  int4* geo = (int4*)d_ws;                                   // 16,000 B
  unsigned int* cnt = (unsigned int*)((char*)d_ws + 16384);  // 2 counters

  hipMemsetAsync(cnt, 0, 2 * sizeof(unsigned int), stream);
  hipLaunchKernelGGL(k_all, dim3(NLOOP + NCOPY), dim3(NTHR), 0, stream,
                     seed, geo, cnt, img, out);
}

// Round 14
// 68.278 us; speedup vs baseline: 19.6813x; 19.6813x over previous
//
#include <hip/hip_runtime.h>
#include <stdint.h>

#define HH 4096
#define WW 4096
#define CC 3
#define NLOOP 1000
#define NCOPY 8192   // dedicated copy blocks in the merged kernel
#define NTHR 256

typedef float vfloat4 __attribute__((ext_vector_type(4)));

struct Desc {
  int psh, psw, ph, pw, wsh, wsw, pad0, pad1;
  unsigned long long mask, live;
  unsigned char src[3][64];
  unsigned char pad[16];
};
static_assert(sizeof(Desc) == 256, "desc size");

// JAX threefry2x32 (20 rounds), exact port of _threefry2x32_lowering.
__device__ __forceinline__ void tf2x32(uint32_t k0, uint32_t k1,
                                       uint32_t x0, uint32_t x1,
                                       uint32_t& o0, uint32_t& o1) {
  const uint32_t ks2 = k0 ^ k1 ^ 0x1BD11BDAu;
  x0 += k0; x1 += k1;
#define ROTL_(v,r) (((v)<<(r))|((v)>>(32-(r))))
#define RND_(r) { x0 += x1; x1 = ROTL_(x1,(r)); x1 ^= x0; }
  RND_(13) RND_(15) RND_(26) RND_(6)
  x0 += k1; x1 += ks2 + 1u;
  RND_(17) RND_(29) RND_(16) RND_(24)
  x0 += ks2; x1 += k0 + 2u;
  RND_(13) RND_(15) RND_(26) RND_(6)
  x0 += k0; x1 += k1 + 3u;
  RND_(17) RND_(29) RND_(16) RND_(24)
  x0 += k1; x1 += ks2 + 4u;
  RND_(13) RND_(15) RND_(26) RND_(6)
  x0 += ks2; x1 += k0 + 5u;
  o0 = x0; o1 = x1;
#undef RND_
#undef ROTL_
}

// 32-bit random_bits under partitionable threefry: XOR of the two output words.
__device__ __forceinline__ uint32_t rb32(uint32_t k0, uint32_t k1,
                                         uint32_t x0, uint32_t x1) {
  uint32_t o0, o1;
  tf2x32(k0, k1, x0, x1, o0, o1);
  return o0 ^ o1;
}

// Merged kernel: blocks [0,NLOOP) derive window descriptors and return;
// blocks [NLOOP, NLOOP+NCOPY) stream-copy img->out.
// Copy: PLAIN loads (let L2/L3 retain the input across replays: 201 MB < 256
// MB L3) + NT stores (output is write-once; don't pollute caches).
__global__ __launch_bounds__(NTHR) void k_desc_copy(
    const int* __restrict__ seedp, Desc* __restrict__ d,
    const vfloat4* __restrict__ in4, vfloat4* __restrict__ out4, int n4) {
  const int b = blockIdx.x;
  if (b >= NLOOP) {
    // ---- copy path ----
    int idx = (b - NLOOP) * NTHR + threadIdx.x;
    const int stride = NCOPY * NTHR;
    for (int i = idx; i < n4; i += stride) {
      vfloat4 v = in4[i];
      __builtin_nontemporal_store(v, &out4[i]);
    }
    return;
  }

  // ---- desc path ----
  const int i = b;
  const int tid = threadIdx.x;
  const int lane = tid & 63;
  const uint32_t K0 = 0u;
  const uint32_t K1 = (uint32_t)seedp[0];

  __shared__ uint32_t rb[CC * 64];
  __shared__ unsigned char mlist[64];
  __shared__ unsigned char srcbuf[64];

  uint32_t k0, k1, a0, a1;
  tf2x32(K0, K1, 0u, (uint32_t)i, k0, k1);

  uint32_t kh0,kh1,kw0,kw1,kp0,kp1,kq0,kq1,kr0,kr1;
  tf2x32(k0,k1,0u,0u,kh0,kh1);   // kh
  tf2x32(k0,k1,0u,1u,kw0,kw1);   // kw
  tf2x32(k0,k1,0u,2u,kp0,kp1);   // kph
  tf2x32(k0,k1,0u,3u,kq0,kq1);   // kpw
  tf2x32(k0,k1,0u,4u,kr0,kr1);   // kperm

  // 192 uniform draws for kperm, one per thread 0..191
  if (tid < CC * 64) rb[tid] = rb32(kr0, kr1, 0u, (uint32_t)tid) >> 9;

  tf2x32(kh0,kh1,0u,1u,a0,a1);   // k2 of randint's internal split
  const int wsh = 1 + (int)(rb32(a0,a1,0u,0u) & 7u);
  tf2x32(kw0,kw1,0u,1u,a0,a1);
  const int wsw = 1 + (int)(rb32(a0,a1,0u,0u) & 7u);

  const float uh = __uint_as_float(0x3F800000u | (rb32(kp0,kp1,0u,0u) >> 9)) - 1.0f;
  const float uw = __uint_as_float(0x3F800000u | (rb32(kq0,kq1,0u,0u) >> 9)) - 1.0f;

  const int ph = (int)(uh * (float)(HH - wsh + 1));
  const int pw = (int)(uw * (float)(WW - wsw + 1));
  const int psh = min(ph, HH - 8);
  const int psw = min(pw, WW - 8);
  const int offh = ph - psh;
  const int offw = pw - psw;

  const uint32_t colm = ((1u << wsw) - 1u) << offw;
  unsigned long long rows = (wsh == 8) ? ~0ull : ((1ull << (8 * wsh)) - 1ull);
  rows <<= (8 * offh);
  const unsigned long long mask =
      rows & (0x0101010101010101ull * (unsigned long long)colm);

  const bool masked = (tid < 64) && (((mask >> lane) & 1ull) != 0ull);
  const int ordinal = __popcll(mask & ((lane == 0) ? 0ull : ((1ull << lane) - 1ull)));
  __syncthreads();                       // rb ready
  if (masked) mlist[ordinal] = (unsigned char)lane;

  for (int c = 0; c < CC; ++c) {
    int rank = 0;
    if (masked) {
      const uint32_t myk = rb[(c << 6) | lane];
      for (int q = 0; q < 64; ++q) {
        if ((mask >> q) & 1ull) {
          const uint32_t kq = rb[(c << 6) | q];
          if (kq < myk || (kq == myk && q < lane)) ++rank;
        }
      }
    }
    if (tid < 64) srcbuf[lane] = (unsigned char)lane;
    __syncthreads();
    if (masked) srcbuf[mlist[rank]] = (unsigned char)lane;
    __syncthreads();
    if (tid < 64) d[i].src[c][lane] = srcbuf[lane];
    __syncthreads();
  }

  if (tid == 0) {
    d[i].psh = psh; d[i].psw = psw; d[i].ph = ph; d[i].pw = pw;
    d[i].wsh = wsh; d[i].wsw = wsw; d[i].mask = mask;
    d[i].pad0 = 0; d[i].pad1 = 0;
  }
}

// Fused: live_i = mask_i minus coverage by later windows; then scatter window i.
__global__ __launch_bounds__(NTHR) void k_live_apply(
    const float* __restrict__ in, float* __restrict__ out,
    Desc* __restrict__ d) {
  const int i = blockIdx.x;
  const int t = threadIdx.x;   // 256
  const int psh = d[i].psh, psw = d[i].psw;
  unsigned long long clr = 0ull;
  for (int j = i + 1 + t; j < NLOOP; j += NTHR) {
    const int phj = d[j].ph, pwj = d[j].pw;
    const int whj = d[j].wsh, wwj = d[j].wsw;
    const int r0 = max(0, phj - psh), r1 = min(8, phj + whj - psh);
    const int c0 = max(0, pwj - psw), c1 = min(8, pwj + wwj - psw);
    if (r0 < r1 && c0 < c1) {
      const uint32_t colm = ((1u << (c1 - c0)) - 1u) << c0;
      const int nr = r1 - r0;
      unsigned long long rows = (nr == 8) ? ~0ull : ((1ull << (8 * nr)) - 1ull);
      rows <<= (8 * r0);
      clr |= rows & (0x0101010101010101ull * (unsigned long long)colm);
    }
  }
  __shared__ unsigned long long sh[NTHR];
  sh[t] = clr;
  __syncthreads();
  for (int s = NTHR / 2; s > 0; s >>= 1) {
    if (t < s) sh[t] |= sh[t + s];
    __syncthreads();
  }
  const unsigned long long live = d[i].mask & ~sh[0];

  // scatter: one thread per (c, q); sources always from the ORIGINAL image
  if (t < CC * 64) {
    const int c = t >> 6, q = t & 63;
    if ((live >> q) & 1ull) {
      const int s = d[i].src[c][q];
      const size_t base = (size_t)c * (size_t)HH * (size_t)WW;
      out[base + (size_t)(psh + (q >> 3)) * WW + (size_t)(psw + (q & 7))] =
          in[base + (size_t)(psh + (s >> 3)) * WW + (size_t)(psw + (s & 7))];
    }
  }
}

extern "C" void kernel_launch(void* const* d_in, const int* in_sizes, int n_in,
                              void* d_out, int out_size, void* d_ws, size_t ws_size,
                              hipStream_t stream) {
  const float* img = (const float*)d_in[0];
  const int* seed = (const int*)d_in[1];
  float* out = (float*)d_out;
  Desc* d = (Desc*)d_ws;   // needs NLOOP*256 = 256 KiB

  const int n4 = (CC * HH * WW) / 4;
  hipLaunchKernelGGL(k_desc_copy, dim3(NLOOP + NCOPY), dim3(NTHR), 0, stream,
                     seed, d, (const vfloat4*)img, (vfloat4*)out, n4);
  hipLaunchKernelGGL(k_live_apply, dim3(NLOOP), dim3(NTHR), 0, stream, img, out, d);
}

// Round 15
// 67.709 us; speedup vs baseline: 19.8469x; 1.0084x over previous
//
#include <hip/hip_runtime.h>
#include <stdint.h>

#define HH 4096
#define WW 4096
#define CC 3
#define NLOOP 1000
#define NCOPY 8192   // dedicated copy blocks in the merged kernel
#define NTHR 256

typedef float vfloat4 __attribute__((ext_vector_type(4)));

struct Desc {
  int psh, psw, ph, pw, wsh, wsw, pad0, pad1;
  unsigned long long mask, live;
  unsigned char src[3][64];
  unsigned char pad[16];
};
static_assert(sizeof(Desc) == 256, "desc size");

// Streaming store: non-temporal + system scope (sc0 sc1 nt) — attempt to
// bypass L2 *and* MALL allocation so the write-once output never evicts the
// L3-resident input. A/B vs __builtin_nontemporal_store (R14: FETCH ~98MB).
__device__ __forceinline__ void stream_store(vfloat4 v, vfloat4* p) {
  asm volatile("global_store_dwordx4 %0, %1, off sc0 sc1 nt"
               :: "v"(p), "v"(v) : "memory");
}

// JAX threefry2x32 (20 rounds), exact port of _threefry2x32_lowering.
__device__ __forceinline__ void tf2x32(uint32_t k0, uint32_t k1,
                                       uint32_t x0, uint32_t x1,
                                       uint32_t& o0, uint32_t& o1) {
  const uint32_t ks2 = k0 ^ k1 ^ 0x1BD11BDAu;
  x0 += k0; x1 += k1;
#define ROTL_(v,r) (((v)<<(r))|((v)>>(32-(r))))
#define RND_(r) { x0 += x1; x1 = ROTL_(x1,(r)); x1 ^= x0; }
  RND_(13) RND_(15) RND_(26) RND_(6)
  x0 += k1; x1 += ks2 + 1u;
  RND_(17) RND_(29) RND_(16) RND_(24)
  x0 += ks2; x1 += k0 + 2u;
  RND_(13) RND_(15) RND_(26) RND_(6)
  x0 += k0; x1 += k1 + 3u;
  RND_(17) RND_(29) RND_(16) RND_(24)
  x0 += k1; x1 += ks2 + 4u;
  RND_(13) RND_(15) RND_(26) RND_(6)
  x0 += ks2; x1 += k0 + 5u;
  o0 = x0; o1 = x1;
#undef RND_
#undef ROTL_
}

// 32-bit random_bits under partitionable threefry: XOR of the two output words.
__device__ __forceinline__ uint32_t rb32(uint32_t k0, uint32_t k1,
                                         uint32_t x0, uint32_t x1) {
  uint32_t o0, o1;
  tf2x32(k0, k1, x0, x1, o0, o1);
  return o0 ^ o1;
}

// Merged kernel: blocks [0,NLOOP) derive window descriptors and return;
// blocks [NLOOP, NLOOP+NCOPY) stream-copy img->out.
// Copy: PLAIN loads (L3 retains input across replays) + sc0/sc1/nt stores.
__global__ __launch_bounds__(NTHR) void k_desc_copy(
    const int* __restrict__ seedp, Desc* __restrict__ d,
    const vfloat4* __restrict__ in4, vfloat4* __restrict__ out4, int n4) {
  const int b = blockIdx.x;
  if (b >= NLOOP) {
    // ---- copy path ----
    int idx = (b - NLOOP) * NTHR + threadIdx.x;
    const int stride = NCOPY * NTHR;
    for (int i = idx; i < n4; i += stride) {
      vfloat4 v = in4[i];
      stream_store(v, &out4[i]);
    }
    asm volatile("s_waitcnt vmcnt(0)" ::: "memory");  // drain before retire
    return;
  }

  // ---- desc path ----
  const int i = b;
  const int tid = threadIdx.x;
  const int lane = tid & 63;
  const uint32_t K0 = 0u;
  const uint32_t K1 = (uint32_t)seedp[0];

  __shared__ uint32_t rb[CC * 64];
  __shared__ unsigned char mlist[64];
  __shared__ unsigned char srcbuf[64];

  uint32_t k0, k1, a0, a1;
  tf2x32(K0, K1, 0u, (uint32_t)i, k0, k1);

  uint32_t kh0,kh1,kw0,kw1,kp0,kp1,kq0,kq1,kr0,kr1;
  tf2x32(k0,k1,0u,0u,kh0,kh1);   // kh
  tf2x32(k0,k1,0u,1u,kw0,kw1);   // kw
  tf2x32(k0,k1,0u,2u,kp0,kp1);   // kph
  tf2x32(k0,k1,0u,3u,kq0,kq1);   // kpw
  tf2x32(k0,k1,0u,4u,kr0,kr1);   // kperm

  // 192 uniform draws for kperm, one per thread 0..191
  if (tid < CC * 64) rb[tid] = rb32(kr0, kr1, 0u, (uint32_t)tid) >> 9;

  tf2x32(kh0,kh1,0u,1u,a0,a1);   // k2 of randint's internal split
  const int wsh = 1 + (int)(rb32(a0,a1,0u,0u) & 7u);
  tf2x32(kw0,kw1,0u,1u,a0,a1);
  const int wsw = 1 + (int)(rb32(a0,a1,0u,0u) & 7u);

  const float uh = __uint_as_float(0x3F800000u | (rb32(kp0,kp1,0u,0u) >> 9)) - 1.0f;
  const float uw = __uint_as_float(0x3F800000u | (rb32(kq0,kq1,0u,0u) >> 9)) - 1.0f;

  const int ph = (int)(uh * (float)(HH - wsh + 1));
  const int pw = (int)(uw * (float)(WW - wsw + 1));
  const int psh = min(ph, HH - 8);
  const int psw = min(pw, WW - 8);
  const int offh = ph - psh;
  const int offw = pw - psw;

  const uint32_t colm = ((1u << wsw) - 1u) << offw;
  unsigned long long rows = (wsh == 8) ? ~0ull : ((1ull << (8 * wsh)) - 1ull);
  rows <<= (8 * offh);
  const unsigned long long mask =
      rows & (0x0101010101010101ull * (unsigned long long)colm);

  const bool masked = (tid < 64) && (((mask >> lane) & 1ull) != 0ull);
  const int ordinal = __popcll(mask & ((lane == 0) ? 0ull : ((1ull << lane) - 1ull)));
  __syncthreads();                       // rb ready
  if (masked) mlist[ordinal] = (unsigned char)lane;

  for (int c = 0; c < CC; ++c) {
    int rank = 0;
    if (masked) {
      const uint32_t myk = rb[(c << 6) | lane];
      for (int q = 0; q < 64; ++q) {
        if ((mask >> q) & 1ull) {
          const uint32_t kq = rb[(c << 6) | q];
          if (kq < myk || (kq == myk && q < lane)) ++rank;
        }
      }
    }
    if (tid < 64) srcbuf[lane] = (unsigned char)lane;
    __syncthreads();
    if (masked) srcbuf[mlist[rank]] = (unsigned char)lane;
    __syncthreads();
    if (tid < 64) d[i].src[c][lane] = srcbuf[lane];
    __syncthreads();
  }

  if (tid == 0) {
    d[i].psh = psh; d[i].psw = psw; d[i].ph = ph; d[i].pw = pw;
    d[i].wsh = wsh; d[i].wsw = wsw; d[i].mask = mask;
    d[i].pad0 = 0; d[i].pad1 = 0;
  }
}

// Fused: live_i = mask_i minus coverage by later windows; then scatter window i.
__global__ __launch_bounds__(NTHR) void k_live_apply(
    const float* __restrict__ in, float* __restrict__ out,
    Desc* __restrict__ d) {
  const int i = blockIdx.x;
  const int t = threadIdx.x;   // 256
  const int psh = d[i].psh, psw = d[i].psw;
  unsigned long long clr = 0ull;
  for (int j = i + 1 + t; j < NLOOP; j += NTHR) {
    const int phj = d[j].ph, pwj = d[j].pw;
    const int whj = d[j].wsh, wwj = d[j].wsw;
    const int r0 = max(0, phj - psh), r1 = min(8, phj + whj - psh);
    const int c0 = max(0, pwj - psw), c1 = min(8, pwj + wwj - psw);
    if (r0 < r1 && c0 < c1) {
      const uint32_t colm = ((1u << (c1 - c0)) - 1u) << c0;
      const int nr = r1 - r0;
      unsigned long long rows = (nr == 8) ? ~0ull : ((1ull << (8 * nr)) - 1ull);
      rows <<= (8 * r0);
      clr |= rows & (0x0101010101010101ull * (unsigned long long)colm);
    }
  }
  __shared__ unsigned long long sh[NTHR];
  sh[t] = clr;
  __syncthreads();
  for (int s = NTHR / 2; s > 0; s >>= 1) {
    if (t < s) sh[t] |= sh[t + s];
    __syncthreads();
  }
  const unsigned long long live = d[i].mask & ~sh[0];

  // scatter: one thread per (c, q); sources always from the ORIGINAL image
  if (t < CC * 64) {
    const int c = t >> 6, q = t & 63;
    if ((live >> q) & 1ull) {
      const int s = d[i].src[c][q];
      const size_t base = (size_t)c * (size_t)HH * (size_t)WW;
      out[base + (size_t)(psh + (q >> 3)) * WW + (size_t)(psw + (q & 7))] =
          in[base + (size_t)(psh + (s >> 3)) * WW + (size_t)(psw + (s & 7))];
    }
  }
}

extern "C" void kernel_launch(void* const* d_in, const int* in_sizes, int n_in,
                              void* d_out, int out_size, void* d_ws, size_t ws_size,
                              hipStream_t stream) {
  const float* img = (const float*)d_in[0];
  const int* seed = (const int*)d_in[1];
  float* out = (float*)d_out;
  Desc* d = (Desc*)d_ws;   // needs NLOOP*256 = 256 KiB

  const int n4 = (CC * HH * WW) / 4;
  hipLaunchKernelGGL(k_desc_copy, dim3(NLOOP + NCOPY), dim3(NTHR), 0, stream,
                     seed, d, (const vfloat4*)img, (vfloat4*)out, n4);
  hipLaunchKernelGGL(k_live_apply, dim3(NLOOP), dim3(NTHR), 0, stream, img, out, d);
}